// Round 6
// baseline (117.759 us; speedup 1.0000x reference)
//
#include <hip/hip_runtime.h>
#include <math.h>

#define NB 8192
#define DK 128
#define TI 128                         // square tile edge (rows == cols)
#define NTILES (NB / TI)               // 64
#define NBLK (NTILES * (NTILES + 1) / 2)  // 2080 upper-triangle blocks
#define NCOMB (NB / 256)               // 32 combine blocks

typedef __attribute__((ext_vector_type(8))) short short8;
typedef __attribute__((ext_vector_type(16))) float float16;

__device__ inline unsigned short f2bf(float f) {
    unsigned int x = __float_as_uint(f);
    unsigned int r = (x + 0x7fffu + ((x >> 16) & 1u)) >> 16;
    return (unsigned short)r;
}

// async global->LDS DMA, 16 B per lane; LDS dest = wave-uniform base + lane*16
__device__ inline void gload_lds16(const unsigned short* g, unsigned short* l) {
    __builtin_amdgcn_global_load_lds(
        (const __attribute__((address_space(1))) unsigned int*)g,
        (__attribute__((address_space(3))) unsigned int*)l, 16, 0, 0);
}

// ---------------- normalize -> bf16, packed meta, and zero accum/ticket ---------
__global__ void norm_kernel(const float* __restrict__ emb, const int* __restrict__ labels,
                            const int* __restrict__ groups, unsigned short* __restrict__ xnb,
                            int* __restrict__ meta, float* __restrict__ accum,
                            int* __restrict__ ticket) {
    int row  = blockIdx.x * 4 + (threadIdx.x >> 6);
    int lane = threadIdx.x & 63;
    float2 v = ((const float2*)(emb + (size_t)row * DK))[lane];
    float ss = v.x * v.x + v.y * v.y;
#pragma unroll
    for (int off = 32; off; off >>= 1) ss += __shfl_xor(ss, off, 64);
    float inv = 1.0f / fmaxf(sqrtf(ss), 1e-12f);
    ushort2 o;
    o.x = f2bf(v.x * inv);
    o.y = f2bf(v.y * inv);
    ((ushort2*)(xnb + (size_t)row * DK))[lane] = o;
    if (lane == 0) meta[row] = (labels[row] << 8) | groups[row];
    if (blockIdx.x == 0 && threadIdx.x == 0) {
        accum[0] = 0.0f; accum[1] = 0.0f; ticket[0] = 0;
    }
}

// ---------------- symmetric (upper-triangle) MFMA gram + two-sided mining -------
// Encoded similarity space (proven):
//   -t = (same_label? 8:0) - s   feeds apn (row) AND apn_col (col side, symmetric)
//    v = s - 8*sl + 4*sg         feeds anc (row) AND anc_col
// C layout (verified): col = lane&31, row = (reg&3) + 8*(reg>>2) + 4*(lane>>5)
//
// part[64][NB] (float2 {apn, anc}): row-side of (ti,tj) -> slot tj (rows of tile ti);
// col-side (ti<tj) -> slot ti (rows of tile tj); diagonal skips col-side.
// Every (slot,row) written exactly once; all 64 slots valid per row.
//
// Staging: entire 128-row B-strip (32 KB) via async global_load_lds at block
// start, ONE barrier, then all 4 tiles computed barrier-free. LDS rows are
// unpadded 256 B; read bank conflicts broken by the T2 XOR swizzle applied on
// the GLOBAL source address (16B chunk ^= row&7) and mirrored on the ds_read.
__global__ __launch_bounds__(256, 3) void mine_tri(
    const unsigned short* __restrict__ xnb, const int* __restrict__ meta,
    float2* __restrict__ part) {
    __shared__ unsigned short Bs[TI * DK];         // 128 rows x 256 B = 32 KB, linear

    // map blockIdx.x -> (ti, tj), ti <= tj
    int bid = blockIdx.x;
    int ti = 0;
    while (bid >= NTILES - ti) { bid -= NTILES - ti; ti++; }
    const int tj = ti + bid;

    const int tid  = threadIdx.x;
    const int w    = tid >> 6;
    const int lane = tid & 63;
    const int half = lane >> 5;
    const int l31  = lane & 31;
    const int i0    = ti * TI;
    const int jbase = tj * TI;
    const int irow  = i0 + w * 32;

    // ---- issue the full strip stage (8 x 16B per thread), swizzled source ----
#pragma unroll
    for (int s = 0; s < 8; s++) {
        int slot = tid + s * 256;                  // 0..2047 ; wave-contiguous
        int row  = slot >> 4;                      // strip row 0..127
        int gch  = (slot & 15) ^ (row & 7);        // inverse == forward (XOR)
        gload_lds16(xnb + (size_t)(jbase + row) * DK + gch * 8, &Bs[slot * 8]);
    }

    // ---- A fragments + meta while the DMA flies ----
    short8 afrag[8];
#pragma unroll
    for (int ks = 0; ks < 8; ks++)
        afrag[ks] = *(const short8*)(xnb + (size_t)(irow + l31) * DK + ks * 16 + half * 8);

    int metaI[16];
    float apn[16], anc[16];
#pragma unroll
    for (int reg = 0; reg < 16; reg++) {
        int r = (reg & 3) + 8 * (reg >> 2) + 4 * half;
        metaI[reg] = meta[irow + r];
        apn[reg] = -1e9f; anc[reg] = -1e9f;
    }
    int mjc[4];
#pragma unroll
    for (int q = 0; q < 4; q++) mjc[q] = meta[jbase + q * 32 + l31];

    float apnC[4], ancC[4];                        // col-side accumulators
#pragma unroll
    for (int q = 0; q < 4; q++) { apnC[q] = -1e9f; ancC[q] = -1e9f; }

    __syncthreads();                               // drains vmcnt: strip resident

    // ---- 4 barrier-free 32x128 MFMA tiles + mining ----
#pragma unroll
    for (int jt = 0; jt < 2; jt++) {
#pragma unroll
        for (int ct = 0; ct < 2; ct++) {
            const int q   = jt * 2 + ct;
            const int bro = q * 32 + l31;          // strip row for B fragment

            float16 c;
#pragma unroll
            for (int e = 0; e < 16; e++) c[e] = 0.0f;
#pragma unroll
            for (int ks = 0; ks < 8; ks++) {
                int ch = ((ks * 2 + half) ^ (bro & 7)) * 8;     // swizzled chunk
                short8 b = *(const short8*)&Bs[bro * DK + ch];
                c = __builtin_amdgcn_mfma_f32_32x32x16_bf16(afrag[ks], b, c, 0, 0, 0);
            }

            const int mj = mjc[q];
#pragma unroll
            for (int reg = 0; reg < 16; reg++) {
                float s = c[reg];
                int x = metaI[reg] ^ mj;
                bool sl = (unsigned)x < 0x100u;    // same label
                float t8 = s - 8.0f;
                float t  = sl ? t8 : s;            // t = s - (sl?8:0)
                float negt = -t;
                apn[reg] = fmaxf(apn[reg], negt);  // row-side (anchor = i)
                apnC[q]  = fmaxf(apnC[q],  negt);  // col-side (anchor = j)
                bool sg = (x & 0xFFu) == 0u;       // same group
                float t4 = t + 4.0f;
                float v  = sg ? t4 : t;            // + (sg?4:0)
                anc[reg] = fmaxf(anc[reg], v);
                ancC[q]  = fmaxf(ancC[q],  v);
            }
        }
    }

    // ---- row side: butterfly reduce across the 32 column-lanes, write slot tj ----
#pragma unroll
    for (int reg = 0; reg < 16; reg++) {
#pragma unroll
        for (int off = 16; off; off >>= 1) {
            apn[reg] = fmaxf(apn[reg], __shfl_xor(apn[reg], off, 64));
            anc[reg] = fmaxf(anc[reg], __shfl_xor(anc[reg], off, 64));
        }
    }
    if (l31 == 0) {
#pragma unroll
        for (int reg = 0; reg < 16; reg++) {
            int r = (reg & 3) + 8 * (reg >> 2) + 4 * half;
            float2 o; o.x = apn[reg]; o.y = anc[reg];
            part[(size_t)tj * NB + (irow + r)] = o;
        }
    }

    // ---- col side: merge halves, cross-wave reduce via LDS, write slot ti ----
    __syncthreads();                               // all Bs reads done; safe to alias
    float* colred = (float*)&Bs[0];                // [2 arr][4 wave][4 q][32 col] = 4 KB
#pragma unroll
    for (int q = 0; q < 4; q++) {
        apnC[q] = fmaxf(apnC[q], __shfl_xor(apnC[q], 32, 64));
        ancC[q] = fmaxf(ancC[q], __shfl_xor(ancC[q], 32, 64));
        if (half == 0) {
            colred[0 * 512 + w * 128 + q * 32 + l31] = apnC[q];
            colred[1 * 512 + w * 128 + q * 32 + l31] = ancC[q];
        }
    }
    __syncthreads();
    if (tid < 128 && ti != tj) {                   // diagonal: col-side == row-side
        int e = tid;                               // q*32 + col within 128-col strip
        float ma = -1e9f, mn = -1e9f;
#pragma unroll
        for (int wv = 0; wv < 4; wv++) {
            ma = fmaxf(ma, colred[0 * 512 + wv * 128 + e]);
            mn = fmaxf(mn, colred[1 * 512 + wv * 128 + e]);
        }
        float2 o; o.x = ma; o.y = mn;
        part[(size_t)ti * NB + (jbase + e)] = o;
    }
}

// ---------------- combine all 64 valid slots + ticketed finalize ----------------
__global__ void combine_kernel(const float2* __restrict__ part,
                               float* __restrict__ accum, int* __restrict__ ticket,
                               float* __restrict__ out) {
    int i = blockIdx.x * 256 + threadIdx.x;
    float a0 = -1e9f, a1 = -1e9f, a2 = -1e9f, a3 = -1e9f;
    float n0 = -1e9f, n1 = -1e9f, n2 = -1e9f, n3 = -1e9f;
#pragma unroll
    for (int s = 0; s < NTILES; s += 4) {
        float2 p0 = part[(size_t)(s + 0) * NB + i];
        float2 p1 = part[(size_t)(s + 1) * NB + i];
        float2 p2 = part[(size_t)(s + 2) * NB + i];
        float2 p3 = part[(size_t)(s + 3) * NB + i];
        a0 = fmaxf(a0, p0.x); n0 = fmaxf(n0, p0.y);
        a1 = fmaxf(a1, p1.x); n1 = fmaxf(n1, p1.y);
        a2 = fmaxf(a2, p2.x); n2 = fmaxf(n2, p2.y);
        a3 = fmaxf(a3, p3.x); n3 = fmaxf(n3, p3.y);
    }
    float apn = fmaxf(fmaxf(a0, a1), fmaxf(a2, a3));
    float anc = fmaxf(fmaxf(n0, n1), fmaxf(n2, n3));

    float anS = (anc > 2.0f) ? anc - 4.0f : anc;
    // loss = anS - (8 - apn) + 0.1 ; suppressed-label values decode to loss <= 0
    float loss = anS + apn - 7.9f;
    float inc = (loss > 0.0f) ? 1.0f : 0.0f;
    float val = inc * loss;

    __shared__ float ssum[4], scnt[4];
#pragma unroll
    for (int off = 32; off; off >>= 1) {
        val += __shfl_xor(val, off, 64);
        inc += __shfl_xor(inc, off, 64);
    }
    int wid = threadIdx.x >> 6, lane = threadIdx.x & 63;
    if (lane == 0) { ssum[wid] = val; scnt[wid] = inc; }
    __syncthreads();
    if (threadIdx.x == 0) {
        float s = 0.f, c = 0.f;
#pragma unroll
        for (int wv = 0; wv < 4; wv++) { s += ssum[wv]; c += scnt[wv]; }
        atomicAdd(&accum[0], s);
        atomicAdd(&accum[1], c);
        __threadfence();                       // release: accum adds visible device-wide
        int old = atomicAdd(ticket, 1);        // device-scope
        if (old == gridDim.x - 1) {            // last block finalizes
            __threadfence();                   // acquire side
            float total = __hip_atomic_load(&accum[0], __ATOMIC_RELAXED, __HIP_MEMORY_SCOPE_AGENT);
            float cnt   = __hip_atomic_load(&accum[1], __ATOMIC_RELAXED, __HIP_MEMORY_SCOPE_AGENT);
            float r = (cnt > 0.0f) ? total / fmaxf(cnt, 1.0f) : 0.0f;
            if (isnan(r)) r = 0.0f;
            out[0] = r;
        }
    }
}

extern "C" void kernel_launch(void* const* d_in, const int* in_sizes, int n_in,
                              void* d_out, int out_size, void* d_ws, size_t ws_size,
                              hipStream_t stream) {
    const float* emb  = (const float*)d_in[0];
    const int* labels = (const int*)d_in[1];
    const int* groups = (const int*)d_in[2];
    float* out = (float*)d_out;

    unsigned short* xnb = (unsigned short*)d_ws;            // 2 MB
    int*    meta   = (int*)(xnb + (size_t)NB * DK);         // 32 KB
    float2* part   = (float2*)(meta + NB);                  // 4 MB: [64][NB] {apn,anc}
    float*  accum  = (float*)(part + (size_t)NTILES * NB);  // 2 floats
    int*    ticket = (int*)(accum + 2);                     // 1 int

    norm_kernel<<<NB / 4, 256, 0, stream>>>(emb, labels, groups, xnb, meta, accum, ticket);
    mine_tri<<<NBLK, 256, 0, stream>>>(xnb, meta, part);
    combine_kernel<<<NCOMB, 256, 0, stream>>>(part, accum, ticket, out);
}

// Round 7
// 107.705 us; speedup vs baseline: 1.0933x; 1.0933x over previous
//
#include <hip/hip_runtime.h>
#include <math.h>

#define NB 8192
#define DK 128
#define TI 128                         // square tile edge (rows == cols)
#define NTILES (NB / TI)               // 64
#define NBLK (NTILES * (NTILES + 1) / 2)  // 2080 upper-triangle blocks
#define BSTRH 136                      // B LDS row stride in bf16 (272 B) -> 0 conflicts (measured r0-r5)
#define NCOMB (NB / 256)               // 32 combine blocks

typedef __attribute__((ext_vector_type(8))) short short8;
typedef __attribute__((ext_vector_type(16))) float float16;

__device__ inline unsigned short f2bf(float f) {
    unsigned int x = __float_as_uint(f);
    unsigned int r = (x + 0x7fffu + ((x >> 16) & 1u)) >> 16;
    return (unsigned short)r;
}

// ---------------- normalize -> bf16, packed meta, and zero accum/ticket ---------
__global__ void norm_kernel(const float* __restrict__ emb, const int* __restrict__ labels,
                            const int* __restrict__ groups, unsigned short* __restrict__ xnb,
                            int* __restrict__ meta, float* __restrict__ accum,
                            int* __restrict__ ticket) {
    int row  = blockIdx.x * 4 + (threadIdx.x >> 6);
    int lane = threadIdx.x & 63;
    float2 v = ((const float2*)(emb + (size_t)row * DK))[lane];
    float ss = v.x * v.x + v.y * v.y;
#pragma unroll
    for (int off = 32; off; off >>= 1) ss += __shfl_xor(ss, off, 64);
    float inv = 1.0f / fmaxf(sqrtf(ss), 1e-12f);
    ushort2 o;
    o.x = f2bf(v.x * inv);
    o.y = f2bf(v.y * inv);
    ((ushort2*)(xnb + (size_t)row * DK))[lane] = o;
    if (lane == 0) meta[row] = (labels[row] << 8) | groups[row];
    if (blockIdx.x == 0 && threadIdx.x == 0) {
        accum[0] = 0.0f; accum[1] = 0.0f; ticket[0] = 0;
    }
}

// ---------------- symmetric (upper-triangle) MFMA gram + two-sided mining -------
// Encoded similarity space (proven):
//   -t = (same_label? 8:0) - s   feeds apn (row) AND apn_col (col side, symmetric)
//    v = s - 8*sl + 4*sg         feeds anc (row) AND anc_col
// C layout (verified): col = lane&31, row = (reg&3) + 8*(reg>>2) + 4*(lane>>5)
//
// part[64][NB] (float2 {apn, anc}): row-side of (ti,tj) -> slot tj (rows of tile ti);
// col-side (ti<tj) -> slot ti (rows of tile tj); diagonal skips col-side.
// Every (slot,row) written exactly once; all 64 slots valid per row.
//
// NOTE __launch_bounds__(256) with NO min-waves arg: rounds 4/6 proved that
// (256,3) on this toolchain caps arch VGPRs at 84 (6-waves/SIMD budget) and
// spills ~31 regs -> ~105 MB scratch traffic/dispatch (VGPR_Count=84,
// FETCH+WRITE ~115 MB). Uncapped, the allocator fits the ~140 live regs.
// Staging: whole 128-row B-strip (34.8 KB padded) staged once with plain
// uint4 loads->stores (BSTRH=136 measured 0 bank conflicts rounds 0-5;
// global_load_lds forces unpadded layout -> 1.06M conflicts in round 6).
__global__ __launch_bounds__(256) void mine_tri(
    const unsigned short* __restrict__ xnb, const int* __restrict__ meta,
    float2* __restrict__ part) {
    __shared__ unsigned short Bs[TI * BSTRH];      // 128 x 272 B = 34816 B

    // map blockIdx.x -> (ti, tj), ti <= tj
    int bid = blockIdx.x;
    int ti = 0;
    while (bid >= NTILES - ti) { bid -= NTILES - ti; ti++; }
    const int tj = ti + bid;

    const int tid  = threadIdx.x;
    const int w    = tid >> 6;
    const int lane = tid & 63;
    const int half = lane >> 5;
    const int l31  = lane & 31;
    const int i0    = ti * TI;
    const int jbase = tj * TI;
    const int irow  = i0 + w * 32;

    // ---- stage the full B-strip once (8 x 16B per thread), padded rows ----
#pragma unroll
    for (int s = 0; s < 8; s++) {
        int slot = tid + s * 256;                  // 0..2047
        int row = slot >> 4, k4 = slot & 15;
        *(uint4*)&Bs[row * BSTRH + k4 * 8] =
            *(const uint4*)(xnb + (size_t)(jbase + row) * DK + k4 * 8);
    }

    // ---- A fragments + meta (global; overlap with other waves' staging) ----
    short8 afrag[8];
#pragma unroll
    for (int ks = 0; ks < 8; ks++)
        afrag[ks] = *(const short8*)(xnb + (size_t)(irow + l31) * DK + ks * 16 + half * 8);

    int metaI[16];
    float apn[16], anc[16];
#pragma unroll
    for (int reg = 0; reg < 16; reg++) {
        int r = (reg & 3) + 8 * (reg >> 2) + 4 * half;
        metaI[reg] = meta[irow + r];
        apn[reg] = -1e9f; anc[reg] = -1e9f;
    }
    int mjc[4];
#pragma unroll
    for (int q = 0; q < 4; q++) mjc[q] = meta[jbase + q * 32 + l31];

    float apnC[4], ancC[4];                        // col-side accumulators
#pragma unroll
    for (int q = 0; q < 4; q++) { apnC[q] = -1e9f; ancC[q] = -1e9f; }

    __syncthreads();                               // strip resident; ONE barrier

    // ---- 4 barrier-free 32x128 MFMA tiles + mining ----
#pragma unroll
    for (int q = 0; q < 4; q++) {
        const int bro = q * 32 + l31;              // strip row for B fragment

        float16 c;
#pragma unroll
        for (int e = 0; e < 16; e++) c[e] = 0.0f;
#pragma unroll
        for (int ks = 0; ks < 8; ks++) {
            short8 b = *(const short8*)&Bs[bro * BSTRH + ks * 16 + half * 8];
            c = __builtin_amdgcn_mfma_f32_32x32x16_bf16(afrag[ks], b, c, 0, 0, 0);
        }

        const int mj = mjc[q];
#pragma unroll
        for (int reg = 0; reg < 16; reg++) {
            float s = c[reg];
            int x = metaI[reg] ^ mj;
            bool sl = (unsigned)x < 0x100u;        // same label
            float t8 = s - 8.0f;
            float t  = sl ? t8 : s;                // t = s - (sl?8:0)
            float negt = -t;
            apn[reg] = fmaxf(apn[reg], negt);      // row-side (anchor = i)
            apnC[q]  = fmaxf(apnC[q],  negt);      // col-side (anchor = j)
            bool sg = (x & 0xFFu) == 0u;           // same group
            float t4 = t + 4.0f;
            float v  = sg ? t4 : t;                // + (sg?4:0)
            anc[reg] = fmaxf(anc[reg], v);
            ancC[q]  = fmaxf(ancC[q],  v);
        }
    }

    // ---- row side: butterfly reduce across the 32 column-lanes, write slot tj ----
#pragma unroll
    for (int reg = 0; reg < 16; reg++) {
#pragma unroll
        for (int off = 16; off; off >>= 1) {
            apn[reg] = fmaxf(apn[reg], __shfl_xor(apn[reg], off, 64));
            anc[reg] = fmaxf(anc[reg], __shfl_xor(anc[reg], off, 64));
        }
    }
    if (l31 == 0) {
#pragma unroll
        for (int reg = 0; reg < 16; reg++) {
            int r = (reg & 3) + 8 * (reg >> 2) + 4 * half;
            float2 o; o.x = apn[reg]; o.y = anc[reg];
            part[(size_t)tj * NB + (irow + r)] = o;
        }
    }

    // ---- col side: merge halves, cross-wave reduce via LDS, write slot ti ----
    __syncthreads();                               // all Bs reads done; safe to alias
    float* colred = (float*)&Bs[0];                // [2 arr][4 wave][4 q][32 col] = 4 KB
#pragma unroll
    for (int q = 0; q < 4; q++) {
        apnC[q] = fmaxf(apnC[q], __shfl_xor(apnC[q], 32, 64));
        ancC[q] = fmaxf(ancC[q], __shfl_xor(ancC[q], 32, 64));
        if (half == 0) {
            colred[0 * 512 + w * 128 + q * 32 + l31] = apnC[q];
            colred[1 * 512 + w * 128 + q * 32 + l31] = ancC[q];
        }
    }
    __syncthreads();
    if (tid < 128 && ti != tj) {                   // diagonal: col-side == row-side
        int e = tid;                               // q*32 + col within 128-col strip
        float ma = -1e9f, mn = -1e9f;
#pragma unroll
        for (int wv = 0; wv < 4; wv++) {
            ma = fmaxf(ma, colred[0 * 512 + wv * 128 + e]);
            mn = fmaxf(mn, colred[1 * 512 + wv * 128 + e]);
        }
        float2 o; o.x = ma; o.y = mn;
        part[(size_t)ti * NB + (jbase + e)] = o;
    }
}

// ---------------- combine all 64 valid slots + ticketed finalize ----------------
__global__ void combine_kernel(const float2* __restrict__ part,
                               float* __restrict__ accum, int* __restrict__ ticket,
                               float* __restrict__ out) {
    int i = blockIdx.x * 256 + threadIdx.x;
    float a0 = -1e9f, a1 = -1e9f, a2 = -1e9f, a3 = -1e9f;
    float n0 = -1e9f, n1 = -1e9f, n2 = -1e9f, n3 = -1e9f;
#pragma unroll
    for (int s = 0; s < NTILES; s += 4) {
        float2 p0 = part[(size_t)(s + 0) * NB + i];
        float2 p1 = part[(size_t)(s + 1) * NB + i];
        float2 p2 = part[(size_t)(s + 2) * NB + i];
        float2 p3 = part[(size_t)(s + 3) * NB + i];
        a0 = fmaxf(a0, p0.x); n0 = fmaxf(n0, p0.y);
        a1 = fmaxf(a1, p1.x); n1 = fmaxf(n1, p1.y);
        a2 = fmaxf(a2, p2.x); n2 = fmaxf(n2, p2.y);
        a3 = fmaxf(a3, p3.x); n3 = fmaxf(n3, p3.y);
    }
    float apn = fmaxf(fmaxf(a0, a1), fmaxf(a2, a3));
    float anc = fmaxf(fmaxf(n0, n1), fmaxf(n2, n3));

    float anS = (anc > 2.0f) ? anc - 4.0f : anc;
    // loss = anS - (8 - apn) + 0.1 ; suppressed-label values decode to loss <= 0
    float loss = anS + apn - 7.9f;
    float inc = (loss > 0.0f) ? 1.0f : 0.0f;
    float val = inc * loss;

    __shared__ float ssum[4], scnt[4];
#pragma unroll
    for (int off = 32; off; off >>= 1) {
        val += __shfl_xor(val, off, 64);
        inc += __shfl_xor(inc, off, 64);
    }
    int wid = threadIdx.x >> 6, lane = threadIdx.x & 63;
    if (lane == 0) { ssum[wid] = val; scnt[wid] = inc; }
    __syncthreads();
    if (threadIdx.x == 0) {
        float s = 0.f, c = 0.f;
#pragma unroll
        for (int wv = 0; wv < 4; wv++) { s += ssum[wv]; c += scnt[wv]; }
        atomicAdd(&accum[0], s);
        atomicAdd(&accum[1], c);
        __threadfence();                       // release: accum adds visible device-wide
        int old = atomicAdd(ticket, 1);        // device-scope
        if (old == gridDim.x - 1) {            // last block finalizes
            __threadfence();                   // acquire side
            float total = __hip_atomic_load(&accum[0], __ATOMIC_RELAXED, __HIP_MEMORY_SCOPE_AGENT);
            float cnt   = __hip_atomic_load(&accum[1], __ATOMIC_RELAXED, __HIP_MEMORY_SCOPE_AGENT);
            float r = (cnt > 0.0f) ? total / fmaxf(cnt, 1.0f) : 0.0f;
            if (isnan(r)) r = 0.0f;
            out[0] = r;
        }
    }
}

extern "C" void kernel_launch(void* const* d_in, const int* in_sizes, int n_in,
                              void* d_out, int out_size, void* d_ws, size_t ws_size,
                              hipStream_t stream) {
    const float* emb  = (const float*)d_in[0];
    const int* labels = (const int*)d_in[1];
    const int* groups = (const int*)d_in[2];
    float* out = (float*)d_out;

    unsigned short* xnb = (unsigned short*)d_ws;            // 2 MB
    int*    meta   = (int*)(xnb + (size_t)NB * DK);         // 32 KB
    float2* part   = (float2*)(meta + NB);                  // 4 MB: [64][NB] {apn,anc}
    float*  accum  = (float*)(part + (size_t)NTILES * NB);  // 2 floats
    int*    ticket = (int*)(accum + 2);                     // 1 int

    norm_kernel<<<NB / 4, 256, 0, stream>>>(emb, labels, groups, xnb, meta, accum, ticket);
    mine_tri<<<NBLK, 256, 0, stream>>>(xnb, meta, part);
    combine_kernel<<<NCOMB, 256, 0, stream>>>(part, accum, ticket, out);
}